// Round 1
// baseline (90452.118 us; speedup 1.0000x reference)
//
#include <hip/hip_runtime.h>
#include <hip/hip_bf16.h>

// ============================================================================
// Seq2Seq (Graves handwriting) forward on MI355X — Round 0 baseline.
// Design: persistent scan kernel (240 blocks x 512 thr, 1 block/CU via LDS),
// 2 global barriers + 1 attention flag per timestep; fp32 VALU GEMVs with
// LDS-staged states; bf16 history + parallel out/loss post-pass.
// ============================================================================

#define B_ 64
#define T_ 400
#define U_ 64
#define E_ 128
#define H_ 400
#define M_ 10
#define NO_ 121

#define NBLK 240
#define NTHR 512
#define P1W  176   // phase-1 LSTM1 worker blocks (64..239)
#define P2W  120   // per-LSTM blocks in phase 2

// ---------------- ws layout (float units) ----------------
constexpr size_t OF_WS2  = 16;                    // w state [64][128]
constexpr size_t OF_KS   = OF_WS2 + 64*128;       // kappa state [64][10]
constexpr size_t OF_N0H  = OF_KS + 640;           // n0h [b][400]
constexpr size_t OF_N0C  = OF_N0H + 25600;        // n0c [n][64]
constexpr size_t OF_N1H  = OF_N0C + 25600;        // n1h [b][400]
constexpr size_t OF_N1C  = OF_N1H + 25600;        // n1c [n][64]
constexpr size_t OF_HA   = OF_N1C + 25600;        // hA  [b][400]
constexpr size_t OF_B0   = OF_HA + 25600;         // bias0 [1600]
constexpr size_t OF_B1   = OF_B0 + 1600;          // bias1 + h2c@Wih1[:,131:531]
constexpr size_t OF_B2   = OF_B1 + 1600;          // bias2 + h2c@Whh2
constexpr size_t OF_OB   = OF_B2 + 1600;          // obias [121] (+pad)
constexpr size_t OF_XT   = OF_OB + 128;           // xT [t][3][64]
constexpr size_t OF_CTX  = OF_XT + (size_t)T_*3*64;     // ctx [b][u][e]
constexpr size_t OF_A0   = OF_CTX + (size_t)64*64*128;  // bf16 n0h_all [t][b][400]
constexpr size_t OF_A1   = OF_A0 + (size_t)T_*64*400/2; // bf16 n1h_all
constexpr size_t WS_FLOATS = OF_A1 + (size_t)T_*64*400/2;

__device__ __forceinline__ float sigf(float x) { return 1.f/(1.f + expf(-x)); }

// ---------------- global barrier (monotonic counter + generation) ----------
__device__ __forceinline__ void gbar(unsigned* cnt, unsigned* gen, unsigned tgt) {
  __syncthreads();
  if (threadIdx.x == 0) {
    __threadfence();
    unsigned prev = __hip_atomic_fetch_add(cnt, 1u, __ATOMIC_ACQ_REL, __HIP_MEMORY_SCOPE_AGENT);
    if (prev == tgt*(unsigned)NBLK - 1u) {
      __hip_atomic_store(gen, tgt, __ATOMIC_RELEASE, __HIP_MEMORY_SCOPE_AGENT);
    } else {
      while (__hip_atomic_load(gen, __ATOMIC_ACQUIRE, __HIP_MEMORY_SCOPE_AGENT) < tgt)
        __builtin_amdgcn_s_sleep(4);
    }
    __threadfence();
  }
  __syncthreads();
}

// ---------------- precompute ----------------
__global__ void k_pre(
  const float* __restrict__ strokes, const int* __restrict__ chars, const float* __restrict__ cmask,
  const float* __restrict__ emb,
  const float* __restrict__ Wih1, const float* __restrict__ Whh2, const float* __restrict__ Wo,
  const float* __restrict__ bih0, const float* __restrict__ bhh0,
  const float* __restrict__ bih1, const float* __restrict__ bhh1,
  const float* __restrict__ bih2, const float* __restrict__ bhh2,
  const float* __restrict__ bo,
  const float* __restrict__ h0, const float* __restrict__ c0,
  const float* __restrict__ w0, const float* __restrict__ k0,
  float* __restrict__ ws)
{
  const int gid = blockIdx.x*blockDim.x + threadIdx.x;
  const int gsz = gridDim.x*blockDim.x;
  float* ctxp = ws + OF_CTX;
  for (int i = gid; i < 64*64*128; i += gsz) {
    int b = i >> 13, rem = i & 8191, u = rem >> 7, e = rem & 127;
    ctxp[i] = emb[chars[b*64+u]*128+e] * cmask[b*64+u];
  }
  float* xT = ws + OF_XT;
  for (int i = gid; i < T_*3*64; i += gsz) {
    int t = i/192, r = i - t*192, j = r >> 6, b = r & 63;
    xT[i] = strokes[(b*T_+t)*3+j];
  }
  const float* h2c = h0 + 800;
  float* b0 = ws + OF_B0; float* b1 = ws + OF_B1; float* b2 = ws + OF_B2;
  for (int r = gid; r < 1600; r += gsz) {
    b0[r] = bih0[r] + bhh0[r];
    float s1 = bih1[r] + bhh1[r];
    const float* w1 = Wih1 + (size_t)r*531 + 131;
    for (int j = 0; j < 400; ++j) s1 += w1[j]*h2c[j];
    b1[r] = s1;
    float s2 = bih2[r] + bhh2[r];
    const float* w2 = Whh2 + (size_t)r*400;
    for (int j = 0; j < 400; ++j) s2 += w2[j]*h2c[j];
    b2[r] = s2;
  }
  float* ob = ws + OF_OB;
  for (int r = gid; r < 121; r += gsz) {
    float s = bo[r];
    const float* wr = Wo + (size_t)r*1200 + 800;
    for (int j = 0; j < 400; ++j) s += wr[j]*h2c[j];
    ob[r] = s;
  }
  float* wS = ws + OF_WS2;
  for (int i = gid; i < 8192; i += gsz) wS[i] = w0[i & 127];
  float* kS = ws + OF_KS;
  for (int i = gid; i < 640; i += gsz) kS[i] = k0[i % 10];
  float* n1hp = ws + OF_N1H; float* n1cp = ws + OF_N1C;
  for (int i = gid; i < 25600; i += gsz) {
    n1hp[i] = h0[400 + (i % 400)];   // [b][j]
    n1cp[i] = c0[400 + (i >> 6)];    // [n][b]
  }
}

// ---------------- hA_0 = LSTM0(x_0, w0 | h0[0], c0[0]) ----------------
__global__ __launch_bounds__(512) void k_init(
  const float* __restrict__ Wih0, const float* __restrict__ Whh0,
  const float* __restrict__ h0, const float* __restrict__ c0, const float* __restrict__ w0,
  float* __restrict__ ws)
{
  const int lane = threadIdx.x & 63;
  const int wv = threadIdx.x >> 6;
  const int n = blockIdx.x*8 + wv;   // 50 blocks * 8 waves = 400
  if (n >= 400) return;
  const float* bias0 = ws + OF_B0;
  const float* xT = ws + OF_XT;
  float* hA = ws + OF_HA;
  float g[4];
  #pragma unroll
  for (int q = 0; q < 4; ++q) {
    int r = q*400 + n;
    const float* wi = Wih0 + (size_t)r*131;
    const float* wh = Whh0 + (size_t)r*400;
    float a = bias0[r];
    a += xT[0*64+lane]*wi[0] + xT[1*64+lane]*wi[1] + xT[2*64+lane]*wi[2];
    for (int e = 0; e < 128; ++e) a += w0[e]*wi[3+e];
    for (int j = 0; j < 400; ++j) a += h0[j]*wh[j];
    g[q] = a;
  }
  float cn = sigf(g[1])*c0[n] + sigf(g[0])*tanhf(g[2]);
  hA[lane*400 + n] = sigf(g[3])*tanhf(cn);
}

// ---------------- gate GEMV: wave = (K-quarter, row-half), lane = batch ------
// virtual K = [x(3) | w(128) | h(400)]; kq0: x+w, kq1..3: h thirds.
__device__ __forceinline__ void gemv8(
    int xt_idx, int lane, int kq, int rh, int ns, int ch,
    const float* __restrict__ bias,
    const float* __restrict__ Wxw, int sxw,
    const float* __restrict__ Whh, int shh, int hoff,
    const float* __restrict__ xT,
    const float* hLs, const float* wLs, float* pLs)
{
  const int hrows = 2*ch;            // rows per wave (half of 4*ch)
  float acc[8]; const float* wrow[8];
  #pragma unroll
  for (int s = 0; s < 8; ++s) {
    if (s < hrows) {
      int rr = rh*hrows + s;
      int q = rr / ch, nl = rr - q*ch;
      int r = __builtin_amdgcn_readfirstlane(q*H_ + ns + nl);
      if (kq == 0) { wrow[s] = Wxw + (size_t)r*sxw;        acc[s] = bias[r]; }
      else         { wrow[s] = Whh + (size_t)r*shh + hoff; acc[s] = 0.f; }
    }
  }
  if (kq == 0) {
    float x0 = xT[(xt_idx*3+0)*64+lane];
    float x1 = xT[(xt_idx*3+1)*64+lane];
    float x2 = xT[(xt_idx*3+2)*64+lane];
    #pragma unroll
    for (int s = 0; s < 8; ++s) if (s < hrows)
      acc[s] += x0*wrow[s][0] + x1*wrow[s][1] + x2*wrow[s][2];
    #pragma unroll 2
    for (int ec = 0; ec < 32; ++ec) {
      float4 w4 = *(const float4*)&wLs[lane*132 + ec*4];
      #pragma unroll
      for (int s = 0; s < 8; ++s) if (s < hrows) {
        const float* wp = wrow[s] + 3 + ec*4;
        acc[s] += w4.x*wp[0] + w4.y*wp[1] + w4.z*wp[2] + w4.w*wp[3];
      }
    }
  } else {
    int jb = (kq==1) ? 0 : (kq==2 ? 33 : 66);
    int je = (kq==1) ? 33 : (kq==2 ? 66 : 100);
    #pragma unroll 2
    for (int jc = jb; jc < je; ++jc) {
      float4 hv = *(const float4*)&hLs[lane*404 + jc*4];
      #pragma unroll
      for (int s = 0; s < 8; ++s) if (s < hrows) {
        const float* wp = wrow[s] + jc*4;
        acc[s] += hv.x*wp[0] + hv.y*wp[1] + hv.z*wp[2] + hv.w*wp[3];
      }
    }
  }
  #pragma unroll
  for (int s = 0; s < 8; ++s) if (s < hrows)
    pLs[((rh*4+kq)*8 + s)*64 + lane] = acc[s];
}

// ---------------- persistent scan ----------------
__global__ __launch_bounds__(NTHR) void k_scan(
  const float* __restrict__ Wih0, const float* __restrict__ Whh0,
  const float* __restrict__ Wih1, const float* __restrict__ Whh1,
  const float* __restrict__ Wih2,
  const float* __restrict__ Wa, const float* __restrict__ ba,
  const float* __restrict__ c0, float* __restrict__ ws)
{
  __shared__ __align__(16) float hLs[64*404];   // h state [b][404]
  __shared__ __align__(16) float wLs[64*132];   // w state [b][132]
  __shared__ float pLs[8*8*64];                 // partials [wave][slot][lane]
  __shared__ float hab[400];
  __shared__ float pA[240];
  __shared__ float aScr[32];
  __shared__ float phL[64];

  const int tid = threadIdx.x;
  const int lane = tid & 63;
  const int wv = __builtin_amdgcn_readfirstlane(tid >> 6);
  const int kq = wv & 3, rh = wv >> 2;
  const int bid = blockIdx.x;

  unsigned* ctrl = (unsigned*)ws;
  float* wS  = ws + OF_WS2;
  float* kS  = ws + OF_KS;
  float* n0h = ws + OF_N0H; float* n0c = ws + OF_N0C;
  float* n1h = ws + OF_N1H; float* n1c = ws + OF_N1C;
  float* hA  = ws + OF_HA;
  const float* bias0 = ws + OF_B0;
  const float* bias1 = ws + OF_B1;
  const float* bias2 = ws + OF_B2;
  const float* xT  = ws + OF_XT;
  const float* ctx = ws + OF_CTX;
  __hip_bfloat16* a0 = (__hip_bfloat16*)(ws + OF_A0);
  __hip_bfloat16* a1 = (__hip_bfloat16*)(ws + OF_A1);

  unsigned bgen = 0;

  for (int t = 0; t < T_; ++t) {
    // ================= phase 1 =================
    if (bid < 64) {
      // -------- attention for batch b = bid --------
      const int b = bid;
      for (int i = tid; i < 400; i += NTHR) hab[i] = hA[b*400+i];
      __syncthreads();
      if (tid < 240) {                   // p = hA @ Wa^T, split 8-way per row
        int r = tid >> 3, seg = tid & 7;
        const float* wr = Wa + r*400 + seg*50;
        const float* hb = hab + seg*50;
        float s = 0.f;
        for (int j = 0; j < 50; ++j) s += hb[j]*wr[j];
        pA[tid] = s;
      }
      __syncthreads();
      if (tid < 30) {
        float s = ba[tid];
        #pragma unroll
        for (int seg = 0; seg < 8; ++seg) s += pA[tid*8+seg];
        float p = expf(s);
        if (tid < 20) aScr[tid] = p;                 // alpha, beta
        else { int m = tid-20; float kn = p + kS[b*10+m]; kS[b*10+m] = kn; aScr[tid] = kn; }
      }
      __syncthreads();
      if (tid < 64) {
        float u = (float)tid, ph = 0.f;
        #pragma unroll
        for (int m = 0; m < 10; ++m) { float d = aScr[20+m]-u; ph += aScr[m]*expf(-aScr[10+m]*d*d); }
        phL[tid] = ph;
      }
      __syncthreads();
      if (tid < 128) {
        float a = 0.f;
        const float* cb = ctx + ((size_t)b*64)*128 + tid;
        for (int u = 0; u < 64; ++u) a += phL[u]*cb[(size_t)u*128];
        wS[b*128+tid] = a;
      }
      __syncthreads();
      if (tid == 0) {
        __threadfence();
        __hip_atomic_fetch_add(&ctrl[2], 1u, __ATOMIC_RELEASE, __HIP_MEMORY_SCOPE_AGENT);
      }
    } else {
      // -------- LSTM1 full gates + combine --------
      const int wb = bid - 64;
      const int ns = (wb*H_)/P1W, ne = ((wb+1)*H_)/P1W, ch = ne-ns;
      for (int i = tid; i < 6400; i += NTHR) {          // stage n1h (prev)
        int b = i/100, jc = i - b*100;
        *(float4*)&hLs[b*404+jc*4] = *(const float4*)&n1h[b*400+jc*4];
      }
      if (tid == 0) {                                    // wait for w_t
        while (__hip_atomic_load(&ctrl[2], __ATOMIC_ACQUIRE, __HIP_MEMORY_SCOPE_AGENT) < 64u*(unsigned)(t+1))
          __builtin_amdgcn_s_sleep(2);
      }
      __syncthreads();
      for (int i = tid; i < 2048; i += NTHR) {           // stage w_t
        int b = i/32, ec = i - b*32;
        *(float4*)&wLs[b*132+ec*4] = *(const float4*)&wS[b*128+ec*4];
      }
      __syncthreads();
      gemv8(t, lane, kq, rh, ns, ch, bias1, Wih1, 531, Whh1, 400, 0, xT, hLs, wLs, pLs);
      __syncthreads();
      const int hrows = 2*ch;
      for (int i = tid; i < ch*64; i += NTHR) {
        int nl = i >> 6, b = i & 63, n = ns+nl;
        float g[4];
        #pragma unroll
        for (int q = 0; q < 4; ++q) {
          int rr = q*ch+nl; int r2 = (rr >= hrows); int s = rr - r2*hrows;
          float v = 0.f;
          #pragma unroll
          for (int k2 = 0; k2 < 4; ++k2) v += pLs[((r2*4+k2)*8+s)*64+b];
          g[q] = v;
        }
        float cp = n1c[n*64+b];
        float cn = sigf(g[1])*cp + sigf(g[0])*tanhf(g[2]);
        float hn = sigf(g[3])*tanhf(cn);
        n0c[n*64+b] = cn;
        n0h[b*400+n] = hn;
        a0[((size_t)t*64+b)*400+n] = __float2bfloat16(hn);
      }
    }
    gbar(&ctrl[0], &ctrl[1], ++bgen);

    // ================= phase 2 =================
    const int isL2 = (bid < P2W);
    if (isL2 || t < T_-1) {
      const int wb2 = isL2 ? bid : bid - P2W;
      const int ns = (wb2*H_)/P2W, ne = ((wb2+1)*H_)/P2W, ch = ne-ns;
      for (int i = tid; i < 6400; i += NTHR) {           // stage n0h (new)
        int b = i/100, jc = i - b*100;
        *(float4*)&hLs[b*404+jc*4] = *(const float4*)&n0h[b*400+jc*4];
      }
      for (int i = tid; i < 2048; i += NTHR) {           // stage w_t
        int b = i/32, ec = i - b*32;
        *(float4*)&wLs[b*132+ec*4] = *(const float4*)&wS[b*128+ec*4];
      }
      __syncthreads();
      if (isL2) gemv8(t,   lane, kq, rh, ns, ch, bias2, Wih2, 531, Wih2, 531, 131, xT, hLs, wLs, pLs);
      else      gemv8(t+1, lane, kq, rh, ns, ch, bias0, Wih0, 131, Whh0, 400, 0,   xT, hLs, wLs, pLs);
      __syncthreads();
      const int hrows = 2*ch;
      for (int i = tid; i < ch*64; i += NTHR) {
        int nl = i >> 6, b = i & 63, n = ns+nl;
        float g[4];
        #pragma unroll
        for (int q = 0; q < 4; ++q) {
          int rr = q*ch+nl; int r2 = (rr >= hrows); int s = rr - r2*hrows;
          float v = 0.f;
          #pragma unroll
          for (int k2 = 0; k2 < 4; ++k2) v += pLs[((r2*4+k2)*8+s)*64+b];
          g[q] = v;
        }
        if (isL2) {
          float cn = sigf(g[1])*c0[800+n] + sigf(g[0])*tanhf(g[2]);
          float hn = sigf(g[3])*tanhf(cn);
          n1c[n*64+b] = cn;
          n1h[b*400+n] = hn;
          a1[((size_t)t*64+b)*400+n] = __float2bfloat16(hn);
        } else {
          float cp = n0c[n*64+b];
          float cn = sigf(g[1])*cp + sigf(g[0])*tanhf(g[2]);
          hA[b*400+n] = sigf(g[3])*tanhf(cn);          // hA_{t+1}
        }
      }
    }
    gbar(&ctrl[0], &ctrl[1], ++bgen);
  }
}

// ---------------- output projection + MDN/eos loss ----------------
__global__ __launch_bounds__(NTHR) void k_outloss(
  const float* __restrict__ Wo, const float* __restrict__ strokes, float* __restrict__ ws)
{
  __shared__ __align__(16) float hL4[64*404];
  __shared__ float oL[121*65];
  const int t = blockIdx.x;
  const int tid = threadIdx.x;
  const int lane = tid & 63;
  const int wv = __builtin_amdgcn_readfirstlane(tid >> 6);
  const float* ob = ws + OF_OB;
  const __hip_bfloat16* a0 = (const __hip_bfloat16*)(ws + OF_A0);
  const __hip_bfloat16* a1 = (const __hip_bfloat16*)(ws + OF_A1);

  float acc[16];
  #pragma unroll
  for (int s = 0; s < 16; ++s) { int r = wv + 8*s; acc[s] = (r < 121) ? ob[r] : 0.f; }

  const unsigned* src0 = (const unsigned*)(a0 + (size_t)t*25600);
  for (int i = tid; i < 12800; i += NTHR) {
    unsigned v = src0[i];
    int b = i/200, jc = i - b*200;
    hL4[b*404+jc*2+0] = __uint_as_float(v << 16);
    hL4[b*404+jc*2+1] = __uint_as_float(v & 0xffff0000u);
  }
  __syncthreads();
  for (int jc = 0; jc < 100; ++jc) {
    float4 hv = *(const float4*)&hL4[lane*404+jc*4];
    #pragma unroll
    for (int s = 0; s < 16; ++s) {
      int r = wv + 8*s;
      if (r < 121) {
        const float* wp = Wo + (size_t)r*1200 + jc*4;
        acc[s] += hv.x*wp[0] + hv.y*wp[1] + hv.z*wp[2] + hv.w*wp[3];
      }
    }
  }
  __syncthreads();
  const unsigned* src1 = (const unsigned*)(a1 + (size_t)t*25600);
  for (int i = tid; i < 12800; i += NTHR) {
    unsigned v = src1[i];
    int b = i/200, jc = i - b*200;
    hL4[b*404+jc*2+0] = __uint_as_float(v << 16);
    hL4[b*404+jc*2+1] = __uint_as_float(v & 0xffff0000u);
  }
  __syncthreads();
  for (int jc = 0; jc < 100; ++jc) {
    float4 hv = *(const float4*)&hL4[lane*404+jc*4];
    #pragma unroll
    for (int s = 0; s < 16; ++s) {
      int r = wv + 8*s;
      if (r < 121) {
        const float* wp = Wo + (size_t)r*1200 + 400 + jc*4;
        acc[s] += hv.x*wp[0] + hv.y*wp[1] + hv.z*wp[2] + hv.w*wp[3];
      }
    }
  }
  #pragma unroll
  for (int s = 0; s < 16; ++s) { int r = wv + 8*s; if (r < 121) oL[r*65+lane] = acc[s]; }
  __syncthreads();

  if (wv == 0) {
    const int b = lane;
    float x0 = strokes[(b*T_+t)*3+0];
    float x1 = strokes[(b*T_+t)*3+1];
    float y  = strokes[(b*T_+t)*3+2];
    float mp = -1e30f;
    #pragma unroll
    for (int k = 0; k < 20; ++k) mp = fmaxf(mp, oL[(80+k)*65+b]);
    float sp = 0.f;
    #pragma unroll
    for (int k = 0; k < 20; ++k) sp += expf(oL[(80+k)*65+b] - mp);
    float lsep = mp + logf(sp);
    float sk[20]; float ms = -1e30f;
    #pragma unroll
    for (int k = 0; k < 20; ++k) {
      float mu0 = oL[(2*k)*65+b],    mu1 = oL[(2*k+1)*65+b];
      float l0  = oL[(40+2*k)*65+b], l1  = oL[(41+2*k)*65+b];
      float rho = tanhf(oL[(100+k)*65+b]);
      float t0 = (x0-mu0)*expf(-l0);
      float t1 = (x1-mu1)*expf(-l1);
      float on = 1.f - rho*rho;
      float Z = t0*t0 + t1*t1 - 2.f*rho*t0*t1;
      float logN = -Z/(2.f*on) - (1.8378770664093453f + l0 + l1 + 0.5f*logf(on));
      float sv = (oL[(80+k)*65+b] - lsep) + logN;
      sk[k] = sv; ms = fmaxf(ms, sv);
    }
    float ss = 0.f;
    #pragma unroll
    for (int k = 0; k < 20; ++k) ss += expf(sk[k]-ms);
    float stroke = -(ms + logf(ss));
    float z = oL[120*65+b];
    float eos = fmaxf(z,0.f) - z*y + log1pf(expf(-fabsf(z)));
    #pragma unroll
    for (int off = 32; off > 0; off >>= 1) {
      stroke += __shfl_down(stroke, off, 64);
      eos    += __shfl_down(eos, off, 64);
    }
    if (lane == 0) { atomicAdd(ws+3, stroke); atomicAdd(ws+4, eos); }
  }
}

__global__ void k_fin(const float* __restrict__ ws, float* __restrict__ out) {
  if (threadIdx.x == 0) {
    out[0] = ws[3] * (1.f/25600.f);
    out[1] = ws[4] * (1.f/25600.f);
  }
}

// ---------------- host ----------------
extern "C" void kernel_launch(void* const* d_in, const int* in_sizes, int n_in,
                              void* d_out, int out_size, void* d_ws, size_t ws_size,
                              hipStream_t stream) {
  const float* strokes = (const float*)d_in[0];
  const int*   chars   = (const int*)d_in[1];
  const float* cmask   = (const float*)d_in[2];
  const float* emb     = (const float*)d_in[3];
  const float* Wih0    = (const float*)d_in[4];
  const float* Whh0    = (const float*)d_in[5];
  const float* bih0    = (const float*)d_in[6];
  const float* bhh0    = (const float*)d_in[7];
  const float* Wih1    = (const float*)d_in[8];
  const float* Whh1    = (const float*)d_in[9];
  const float* bih1    = (const float*)d_in[10];
  const float* bhh1    = (const float*)d_in[11];
  const float* Wih2    = (const float*)d_in[12];
  const float* Whh2    = (const float*)d_in[13];
  const float* bih2    = (const float*)d_in[14];
  const float* bhh2    = (const float*)d_in[15];
  const float* Wa      = (const float*)d_in[16];
  const float* ba      = (const float*)d_in[17];
  const float* Wo      = (const float*)d_in[18];
  const float* bo      = (const float*)d_in[19];
  const float* h0      = (const float*)d_in[20];
  const float* c0      = (const float*)d_in[21];
  const float* w0      = (const float*)d_in[22];
  const float* k0      = (const float*)d_in[23];
  float* ws = (float*)d_ws;
  float* out = (float*)d_out;
  if (ws_size < WS_FLOATS*sizeof(float)) return;  // ~44 MB required

  hipMemsetAsync(d_ws, 0, 64, stream);  // barrier counters + loss accumulators
  k_pre<<<256, 256, 0, stream>>>(strokes, chars, cmask, emb, Wih1, Whh2, Wo,
                                 bih0, bhh0, bih1, bhh1, bih2, bhh2, bo,
                                 h0, c0, w0, k0, ws);
  k_init<<<50, 512, 0, stream>>>(Wih0, Whh0, h0, c0, w0, ws);
  k_scan<<<NBLK, NTHR, 0, stream>>>(Wih0, Whh0, Wih1, Whh1, Wih2, Wa, ba, c0, ws);
  k_outloss<<<T_, NTHR, 0, stream>>>(Wo, strokes, ws);
  k_fin<<<1, 64, 0, stream>>>(ws, out);
}

// Round 2
// 33735.391 us; speedup vs baseline: 2.6812x; 2.6812x over previous
//
#include <hip/hip_runtime.h>
#include <hip/hip_bf16.h>

// ============================================================================
// Seq2Seq (Graves handwriting) forward on MI355X — Round 1.
// Persistent scan kernel, 100 blocks x 512 thr (1 block/CU via LDS).
// 3 global barriers per timestep: [attn] [LSTM1] [LSTM2 ; LSTM0_{t+1}].
// Barrier v2: release-RMW arrival, RELAXED spin + single acquire fence,
// control words on separate cachelines. fp32 VALU GEMVs, LDS-staged states.
// ============================================================================

#define B_ 64
#define T_ 400
#define U_ 64
#define E_ 128
#define H_ 400
#define M_ 10
#define NO_ 121

#define NBLK 100
#define NTHR 512

// ---------------- ws layout (float units) ----------------
// words 0..127 = control: cnt@0, gen@32, lossS@64, lossE@65 (separate lines)
constexpr size_t OF_WS2  = 128;                   // w state [64][128]
constexpr size_t OF_KS   = OF_WS2 + 64*128;       // kappa state [64][10]
constexpr size_t OF_N0H  = OF_KS + 640;           // n0h [b][400]
constexpr size_t OF_N0C  = OF_N0H + 25600;        // n0c [n][64]
constexpr size_t OF_N1H  = OF_N0C + 25600;        // n1h [b][400]
constexpr size_t OF_N1C  = OF_N1H + 25600;        // n1c [n][64]
constexpr size_t OF_HA   = OF_N1C + 25600;        // hA  [b][400]
constexpr size_t OF_B0   = OF_HA + 25600;         // bias0 [1600]
constexpr size_t OF_B1   = OF_B0 + 1600;          // bias1 + h2c@Wih1[:,131:531]
constexpr size_t OF_B2   = OF_B1 + 1600;          // bias2 + h2c@Whh2
constexpr size_t OF_OB   = OF_B2 + 1600;          // obias [121] (+pad)
constexpr size_t OF_XT   = OF_OB + 128;           // xT [t][3][64]
constexpr size_t OF_CTX  = OF_XT + (size_t)T_*3*64;     // ctx [b][u][e]
constexpr size_t OF_A0   = OF_CTX + (size_t)64*64*128;  // bf16 n0h_all [t][b][400]
constexpr size_t OF_A1   = OF_A0 + (size_t)T_*64*400/2; // bf16 n1h_all
constexpr size_t WS_FLOATS = OF_A1 + (size_t)T_*64*400/2;

__device__ __forceinline__ float sigf(float x) { return 1.f/(1.f + expf(-x)); }

// ---------------- global barrier v2 ----------------
// arrival: one RELEASE fetch_add (flushes this XCD's dirty L2 once);
// wait: RELAXED spin with backoff; then ONE acquire fence (L1/L2 inv).
__device__ __forceinline__ void gbar(unsigned* cnt, unsigned* gen, unsigned tgt) {
  __syncthreads();
  if (threadIdx.x == 0) {
    unsigned prev = __hip_atomic_fetch_add(cnt, 1u, __ATOMIC_RELEASE, __HIP_MEMORY_SCOPE_AGENT);
    if (prev == tgt*(unsigned)NBLK - 1u) {
      __hip_atomic_store(gen, tgt, __ATOMIC_RELEASE, __HIP_MEMORY_SCOPE_AGENT);
    } else {
      while (__hip_atomic_load(gen, __ATOMIC_RELAXED, __HIP_MEMORY_SCOPE_AGENT) < tgt)
        __builtin_amdgcn_s_sleep(2);
    }
    __builtin_amdgcn_fence(__ATOMIC_ACQUIRE, "agent");
  }
  __syncthreads();
}

// ---------------- precompute ----------------
__global__ void k_pre(
  const float* __restrict__ strokes, const int* __restrict__ chars, const float* __restrict__ cmask,
  const float* __restrict__ emb,
  const float* __restrict__ Wih1, const float* __restrict__ Whh2, const float* __restrict__ Wo,
  const float* __restrict__ bih0, const float* __restrict__ bhh0,
  const float* __restrict__ bih1, const float* __restrict__ bhh1,
  const float* __restrict__ bih2, const float* __restrict__ bhh2,
  const float* __restrict__ bo,
  const float* __restrict__ h0, const float* __restrict__ c0,
  const float* __restrict__ w0, const float* __restrict__ k0,
  float* __restrict__ ws)
{
  const int gid = blockIdx.x*blockDim.x + threadIdx.x;
  const int gsz = gridDim.x*blockDim.x;
  float* ctxp = ws + OF_CTX;
  for (int i = gid; i < 64*64*128; i += gsz) {
    int b = i >> 13, rem = i & 8191, u = rem >> 7, e = rem & 127;
    ctxp[i] = emb[chars[b*64+u]*128+e] * cmask[b*64+u];
  }
  float* xT = ws + OF_XT;
  for (int i = gid; i < T_*3*64; i += gsz) {
    int t = i/192, r = i - t*192, j = r >> 6, b = r & 63;
    xT[i] = strokes[(b*T_+t)*3+j];
  }
  const float* h2c = h0 + 800;
  float* b0 = ws + OF_B0; float* b1 = ws + OF_B1; float* b2 = ws + OF_B2;
  for (int r = gid; r < 1600; r += gsz) {
    b0[r] = bih0[r] + bhh0[r];
    float s1 = bih1[r] + bhh1[r];
    const float* w1 = Wih1 + (size_t)r*531 + 131;
    for (int j = 0; j < 400; ++j) s1 += w1[j]*h2c[j];
    b1[r] = s1;
    float s2 = bih2[r] + bhh2[r];
    const float* w2 = Whh2 + (size_t)r*400;
    for (int j = 0; j < 400; ++j) s2 += w2[j]*h2c[j];
    b2[r] = s2;
  }
  float* ob = ws + OF_OB;
  for (int r = gid; r < 121; r += gsz) {
    float s = bo[r];
    const float* wr = Wo + (size_t)r*1200 + 800;
    for (int j = 0; j < 400; ++j) s += wr[j]*h2c[j];
    ob[r] = s;
  }
  float* wS = ws + OF_WS2;
  for (int i = gid; i < 8192; i += gsz) wS[i] = w0[i & 127];
  float* kS = ws + OF_KS;
  for (int i = gid; i < 640; i += gsz) kS[i] = k0[i % 10];
  float* n1hp = ws + OF_N1H; float* n1cp = ws + OF_N1C;
  for (int i = gid; i < 25600; i += gsz) {
    n1hp[i] = h0[400 + (i % 400)];   // [b][j]
    n1cp[i] = c0[400 + (i >> 6)];    // [n][b]
  }
}

// ---------------- hA_0 = LSTM0(x_0, w0 | h0[0], c0[0]) ----------------
__global__ __launch_bounds__(512) void k_init(
  const float* __restrict__ Wih0, const float* __restrict__ Whh0,
  const float* __restrict__ h0, const float* __restrict__ c0, const float* __restrict__ w0,
  float* __restrict__ ws)
{
  const int lane = threadIdx.x & 63;
  const int wv = threadIdx.x >> 6;
  const int n = blockIdx.x*8 + wv;   // 50 blocks * 8 waves = 400
  if (n >= 400) return;
  const float* bias0 = ws + OF_B0;
  const float* xT = ws + OF_XT;
  float* hA = ws + OF_HA;
  float g[4];
  #pragma unroll
  for (int q = 0; q < 4; ++q) {
    int r = q*400 + n;
    const float* wi = Wih0 + (size_t)r*131;
    const float* wh = Whh0 + (size_t)r*400;
    float a = bias0[r];
    a += xT[0*64+lane]*wi[0] + xT[1*64+lane]*wi[1] + xT[2*64+lane]*wi[2];
    for (int e = 0; e < 128; ++e) a += w0[e]*wi[3+e];
    for (int j = 0; j < 400; ++j) a += h0[j]*wh[j];
    g[q] = a;
  }
  float cn = sigf(g[1])*c0[n] + sigf(g[0])*tanhf(g[2]);
  hA[lane*400 + n] = sigf(g[3])*tanhf(cn);
}

// ---------------- gate GEMV: wave = (K-quarter, row-half), lane = batch ------
// virtual K = [x(3) | w(128) | h(400)]; kq0: x+w, kq1..3: h thirds.
__device__ __forceinline__ void gemv8(
    int xt_idx, int lane, int kq, int rh, int ns, int ch,
    const float* __restrict__ bias,
    const float* __restrict__ Wxw, int sxw,
    const float* __restrict__ Whh, int shh, int hoff,
    const float* __restrict__ xT,
    const float* hLs, const float* wLs, float* pLs)
{
  const int hrows = 2*ch;            // rows per wave (half of 4*ch)
  float acc[8]; const float* wrow[8];
  #pragma unroll
  for (int s = 0; s < 8; ++s) {
    if (s < hrows) {
      int rr = rh*hrows + s;
      int q = rr / ch, nl = rr - q*ch;
      int r = __builtin_amdgcn_readfirstlane(q*H_ + ns + nl);
      if (kq == 0) { wrow[s] = Wxw + (size_t)r*sxw;        acc[s] = bias[r]; }
      else         { wrow[s] = Whh + (size_t)r*shh + hoff; acc[s] = 0.f; }
    }
  }
  if (kq == 0) {
    float x0 = xT[(xt_idx*3+0)*64+lane];
    float x1 = xT[(xt_idx*3+1)*64+lane];
    float x2 = xT[(xt_idx*3+2)*64+lane];
    #pragma unroll
    for (int s = 0; s < 8; ++s) if (s < hrows)
      acc[s] += x0*wrow[s][0] + x1*wrow[s][1] + x2*wrow[s][2];
    #pragma unroll 2
    for (int ec = 0; ec < 32; ++ec) {
      float4 w4 = *(const float4*)&wLs[lane*132 + ec*4];
      #pragma unroll
      for (int s = 0; s < 8; ++s) if (s < hrows) {
        const float* wp = wrow[s] + 3 + ec*4;
        acc[s] += w4.x*wp[0] + w4.y*wp[1] + w4.z*wp[2] + w4.w*wp[3];
      }
    }
  } else {
    int jb = (kq==1) ? 0 : (kq==2 ? 33 : 66);
    int je = (kq==1) ? 33 : (kq==2 ? 66 : 100);
    #pragma unroll 2
    for (int jc = jb; jc < je; ++jc) {
      float4 hv = *(const float4*)&hLs[lane*404 + jc*4];
      #pragma unroll
      for (int s = 0; s < 8; ++s) if (s < hrows) {
        const float* wp = wrow[s] + jc*4;
        acc[s] += hv.x*wp[0] + hv.y*wp[1] + hv.z*wp[2] + hv.w*wp[3];
      }
    }
  }
  #pragma unroll
  for (int s = 0; s < 8; ++s) if (s < hrows)
    pLs[((rh*4+kq)*8 + s)*64 + lane] = acc[s];
}

// ---------------- persistent scan ----------------
__global__ __launch_bounds__(NTHR) void k_scan(
  const float* __restrict__ Wih0, const float* __restrict__ Whh0,
  const float* __restrict__ Wih1, const float* __restrict__ Whh1,
  const float* __restrict__ Wih2,
  const float* __restrict__ Wa, const float* __restrict__ ba,
  const float* __restrict__ c0, float* __restrict__ ws)
{
  __shared__ __align__(16) float hLs[64*404];   // h state [b][404]
  __shared__ __align__(16) float wLs[64*132];   // w state [b][132]
  __shared__ float pLs[8*8*64];                 // partials [wave][slot][lane]
  __shared__ float hab[400];
  __shared__ float pA[240];
  __shared__ float aScr[32];
  __shared__ float phL[64];

  const int tid = threadIdx.x;
  const int lane = tid & 63;
  const int wv = __builtin_amdgcn_readfirstlane(tid >> 6);
  const int kq = wv & 3, rh = wv >> 2;
  const int bid = blockIdx.x;
  const int ns = bid*4;              // 4 hidden units per block, exact

  unsigned* ctrl = (unsigned*)ws;
  unsigned* cnt = &ctrl[0];
  unsigned* gen = &ctrl[32];
  float* wS  = ws + OF_WS2;
  float* kS  = ws + OF_KS;
  float* n0h = ws + OF_N0H; float* n0c = ws + OF_N0C;
  float* n1h = ws + OF_N1H; float* n1c = ws + OF_N1C;
  float* hA  = ws + OF_HA;
  const float* bias0 = ws + OF_B0;
  const float* bias1 = ws + OF_B1;
  const float* bias2 = ws + OF_B2;
  const float* xT  = ws + OF_XT;
  const float* ctx = ws + OF_CTX;
  __hip_bfloat16* a0 = (__hip_bfloat16*)(ws + OF_A0);
  __hip_bfloat16* a1 = (__hip_bfloat16*)(ws + OF_A1);

  unsigned bgen = 0;

  for (int t = 0; t < T_; ++t) {
    // ================= phase A: attention (blocks 0..63) + prestage n1h =====
    if (bid < 64) {
      const int b = bid;
      for (int i = tid; i < 400; i += NTHR) hab[i] = hA[b*400+i];
      __syncthreads();
      if (tid < 240) {                   // p = hA @ Wa^T, split 8-way per row
        int r = tid >> 3, seg = tid & 7;
        const float* wr = Wa + r*400 + seg*50;
        const float* hb = hab + seg*50;
        float s = 0.f;
        for (int j = 0; j < 50; ++j) s += hb[j]*wr[j];
        pA[tid] = s;
      }
      __syncthreads();
      if (tid < 30) {
        float s = ba[tid];
        #pragma unroll
        for (int seg = 0; seg < 8; ++seg) s += pA[tid*8+seg];
        float p = expf(s);
        if (tid < 20) aScr[tid] = p;                 // alpha, beta
        else { int m = tid-20; float kn = p + kS[b*10+m]; kS[b*10+m] = kn; aScr[tid] = kn; }
      }
      __syncthreads();
      if (tid < 64) {
        float u = (float)tid, ph = 0.f;
        #pragma unroll
        for (int m = 0; m < 10; ++m) { float d = aScr[20+m]-u; ph += aScr[m]*expf(-aScr[10+m]*d*d); }
        phL[tid] = ph;
      }
      __syncthreads();
      if (tid < 128) {
        float a = 0.f;
        const float* cb = ctx + ((size_t)b*64)*128 + tid;
        for (int u = 0; u < 64; ++u) a += phL[u]*cb[(size_t)u*128];
        wS[b*128+tid] = a;
      }
    }
    // prestage hLs <- n1h (previous step's LSTM2 output; LSTM1's h-state)
    for (int i = tid; i < 6400; i += NTHR) {
      int b = i/100, jc = i - b*100;
      *(float4*)&hLs[b*404+jc*4] = *(const float4*)&n1h[b*400+jc*4];
    }
    gbar(cnt, gen, ++bgen);

    // ================= phase B: LSTM1 =================
    for (int i = tid; i < 2048; i += NTHR) {           // stage w_t
      int b = i/32, ec = i - b*32;
      *(float4*)&wLs[b*132+ec*4] = *(const float4*)&wS[b*128+ec*4];
    }
    __syncthreads();
    gemv8(t, lane, kq, rh, ns, 4, bias1, Wih1, 531, Whh1, 400, 0, xT, hLs, wLs, pLs);
    __syncthreads();
    for (int i = tid; i < 256; i += NTHR) {
      int nl = i >> 6, b = i & 63, n = ns+nl;
      float g[4];
      #pragma unroll
      for (int q = 0; q < 4; ++q) {
        int rr = q*4+nl; int r2 = (rr >= 8); int s = rr - r2*8;
        float v = 0.f;
        #pragma unroll
        for (int k2 = 0; k2 < 4; ++k2) v += pLs[((r2*4+k2)*8+s)*64+b];
        g[q] = v;
      }
      float cp = n1c[n*64+b];
      float cn = sigf(g[1])*cp + sigf(g[0])*tanhf(g[2]);
      float hn = sigf(g[3])*tanhf(cn);
      n0c[n*64+b] = cn;
      n0h[b*400+n] = hn;
      a0[((size_t)t*64+b)*400+n] = __float2bfloat16(hn);
    }
    gbar(cnt, gen, ++bgen);

    // ================= phase C: LSTM2, then LSTM0_{t+1} (both use n0h) ======
    for (int i = tid; i < 6400; i += NTHR) {           // stage n0h (new)
      int b = i/100, jc = i - b*100;
      *(float4*)&hLs[b*404+jc*4] = *(const float4*)&n0h[b*400+jc*4];
    }
    __syncthreads();                                   // wLs still holds w_t
    gemv8(t, lane, kq, rh, ns, 4, bias2, Wih2, 531, Wih2, 531, 131, xT, hLs, wLs, pLs);
    __syncthreads();
    for (int i = tid; i < 256; i += NTHR) {
      int nl = i >> 6, b = i & 63, n = ns+nl;
      float g[4];
      #pragma unroll
      for (int q = 0; q < 4; ++q) {
        int rr = q*4+nl; int r2 = (rr >= 8); int s = rr - r2*8;
        float v = 0.f;
        #pragma unroll
        for (int k2 = 0; k2 < 4; ++k2) v += pLs[((r2*4+k2)*8+s)*64+b];
        g[q] = v;
      }
      float cn = sigf(g[1])*c0[800+n] + sigf(g[0])*tanhf(g[2]);
      float hn = sigf(g[3])*tanhf(cn);
      n1c[n*64+b] = cn;
      n1h[b*400+n] = hn;
      a1[((size_t)t*64+b)*400+n] = __float2bfloat16(hn);
    }
    __syncthreads();                                   // pLs reuse guard
    if (t < T_-1) {
      gemv8(t+1, lane, kq, rh, ns, 4, bias0, Wih0, 131, Whh0, 400, 0, xT, hLs, wLs, pLs);
      __syncthreads();
      for (int i = tid; i < 256; i += NTHR) {
        int nl = i >> 6, b = i & 63, n = ns+nl;
        float g[4];
        #pragma unroll
        for (int q = 0; q < 4; ++q) {
          int rr = q*4+nl; int r2 = (rr >= 8); int s = rr - r2*8;
          float v = 0.f;
          #pragma unroll
          for (int k2 = 0; k2 < 4; ++k2) v += pLs[((r2*4+k2)*8+s)*64+b];
          g[q] = v;
        }
        float cp = n0c[n*64+b];
        float cn = sigf(g[1])*cp + sigf(g[0])*tanhf(g[2]);
        hA[b*400+n] = sigf(g[3])*tanhf(cn);            // hA_{t+1}
      }
    }
    gbar(cnt, gen, ++bgen);
  }
}

// ---------------- output projection + MDN/eos loss ----------------
__global__ __launch_bounds__(NTHR) void k_outloss(
  const float* __restrict__ Wo, const float* __restrict__ strokes, float* __restrict__ ws)
{
  __shared__ __align__(16) float hL4[64*404];
  __shared__ float oL[121*65];
  const int t = blockIdx.x;
  const int tid = threadIdx.x;
  const int lane = tid & 63;
  const int wv = __builtin_amdgcn_readfirstlane(tid >> 6);
  const float* ob = ws + OF_OB;
  const __hip_bfloat16* a0 = (const __hip_bfloat16*)(ws + OF_A0);
  const __hip_bfloat16* a1 = (const __hip_bfloat16*)(ws + OF_A1);

  float acc[16];
  #pragma unroll
  for (int s = 0; s < 16; ++s) { int r = wv + 8*s; acc[s] = (r < 121) ? ob[r] : 0.f; }

  const unsigned* src0 = (const unsigned*)(a0 + (size_t)t*25600);
  for (int i = tid; i < 12800; i += NTHR) {
    unsigned v = src0[i];
    int b = i/200, jc = i - b*200;
    hL4[b*404+jc*2+0] = __uint_as_float(v << 16);
    hL4[b*404+jc*2+1] = __uint_as_float(v & 0xffff0000u);
  }
  __syncthreads();
  for (int jc = 0; jc < 100; ++jc) {
    float4 hv = *(const float4*)&hL4[lane*404+jc*4];
    #pragma unroll
    for (int s = 0; s < 16; ++s) {
      int r = wv + 8*s;
      if (r < 121) {
        const float* wp = Wo + (size_t)r*1200 + jc*4;
        acc[s] += hv.x*wp[0] + hv.y*wp[1] + hv.z*wp[2] + hv.w*wp[3];
      }
    }
  }
  __syncthreads();
  const unsigned* src1 = (const unsigned*)(a1 + (size_t)t*25600);
  for (int i = tid; i < 12800; i += NTHR) {
    unsigned v = src1[i];
    int b = i/200, jc = i - b*200;
    hL4[b*404+jc*2+0] = __uint_as_float(v << 16);
    hL4[b*404+jc*2+1] = __uint_as_float(v & 0xffff0000u);
  }
  __syncthreads();
  for (int jc = 0; jc < 100; ++jc) {
    float4 hv = *(const float4*)&hL4[lane*404+jc*4];
    #pragma unroll
    for (int s = 0; s < 16; ++s) {
      int r = wv + 8*s;
      if (r < 121) {
        const float* wp = Wo + (size_t)r*1200 + 400 + jc*4;
        acc[s] += hv.x*wp[0] + hv.y*wp[1] + hv.z*wp[2] + hv.w*wp[3];
      }
    }
  }
  #pragma unroll
  for (int s = 0; s < 16; ++s) { int r = wv + 8*s; if (r < 121) oL[r*65+lane] = acc[s]; }
  __syncthreads();

  if (wv == 0) {
    const int b = lane;
    float x0 = strokes[(b*T_+t)*3+0];
    float x1 = strokes[(b*T_+t)*3+1];
    float y  = strokes[(b*T_+t)*3+2];
    float mp = -1e30f;
    #pragma unroll
    for (int k = 0; k < 20; ++k) mp = fmaxf(mp, oL[(80+k)*65+b]);
    float sp = 0.f;
    #pragma unroll
    for (int k = 0; k < 20; ++k) sp += expf(oL[(80+k)*65+b] - mp);
    float lsep = mp + logf(sp);
    float sk[20]; float ms = -1e30f;
    #pragma unroll
    for (int k = 0; k < 20; ++k) {
      float mu0 = oL[(2*k)*65+b],    mu1 = oL[(2*k+1)*65+b];
      float l0  = oL[(40+2*k)*65+b], l1  = oL[(41+2*k)*65+b];
      float rho = tanhf(oL[(100+k)*65+b]);
      float t0 = (x0-mu0)*expf(-l0);
      float t1 = (x1-mu1)*expf(-l1);
      float on = 1.f - rho*rho;
      float Z = t0*t0 + t1*t1 - 2.f*rho*t0*t1;
      float logN = -Z/(2.f*on) - (1.8378770664093453f + l0 + l1 + 0.5f*logf(on));
      float sv = (oL[(80+k)*65+b] - lsep) + logN;
      sk[k] = sv; ms = fmaxf(ms, sv);
    }
    float ss = 0.f;
    #pragma unroll
    for (int k = 0; k < 20; ++k) ss += expf(sk[k]-ms);
    float stroke = -(ms + logf(ss));
    float z = oL[120*65+b];
    float eos = fmaxf(z,0.f) - z*y + log1pf(expf(-fabsf(z)));
    #pragma unroll
    for (int off = 32; off > 0; off >>= 1) {
      stroke += __shfl_down(stroke, off, 64);
      eos    += __shfl_down(eos, off, 64);
    }
    if (lane == 0) { atomicAdd(ws+64, stroke); atomicAdd(ws+65, eos); }
  }
}

__global__ void k_fin(const float* __restrict__ ws, float* __restrict__ out) {
  if (threadIdx.x == 0) {
    out[0] = ws[64] * (1.f/25600.f);
    out[1] = ws[65] * (1.f/25600.f);
  }
}

// ---------------- host ----------------
extern "C" void kernel_launch(void* const* d_in, const int* in_sizes, int n_in,
                              void* d_out, int out_size, void* d_ws, size_t ws_size,
                              hipStream_t stream) {
  const float* strokes = (const float*)d_in[0];
  const int*   chars   = (const int*)d_in[1];
  const float* cmask   = (const float*)d_in[2];
  const float* emb     = (const float*)d_in[3];
  const float* Wih0    = (const float*)d_in[4];
  const float* Whh0    = (const float*)d_in[5];
  const float* bih0    = (const float*)d_in[6];
  const float* bhh0    = (const float*)d_in[7];
  const float* Wih1    = (const float*)d_in[8];
  const float* Whh1    = (const float*)d_in[9];
  const float* bih1    = (const float*)d_in[10];
  const float* bhh1    = (const float*)d_in[11];
  const float* Wih2    = (const float*)d_in[12];
  const float* Whh2    = (const float*)d_in[13];
  const float* bih2    = (const float*)d_in[14];
  const float* bhh2    = (const float*)d_in[15];
  const float* Wa      = (const float*)d_in[16];
  const float* ba      = (const float*)d_in[17];
  const float* Wo      = (const float*)d_in[18];
  const float* bo      = (const float*)d_in[19];
  const float* h0      = (const float*)d_in[20];
  const float* c0      = (const float*)d_in[21];
  const float* w0      = (const float*)d_in[22];
  const float* k0      = (const float*)d_in[23];
  float* ws = (float*)d_ws;
  float* out = (float*)d_out;
  if (ws_size < WS_FLOATS*sizeof(float)) return;  // ~44 MB required

  hipMemsetAsync(d_ws, 0, 512, stream);  // control words + loss accumulators
  k_pre<<<256, 256, 0, stream>>>(strokes, chars, cmask, emb, Wih1, Whh2, Wo,
                                 bih0, bhh0, bih1, bhh1, bih2, bhh2, bo,
                                 h0, c0, w0, k0, ws);
  k_init<<<50, 512, 0, stream>>>(Wih0, Whh0, h0, c0, w0, ws);
  k_scan<<<NBLK, NTHR, 0, stream>>>(Wih0, Whh0, Wih1, Whh1, Wih2, Wa, ba, c0, ws);
  k_outloss<<<T_, NTHR, 0, stream>>>(Wo, strokes, ws);
  k_fin<<<1, 64, 0, stream>>>(ws, out);
}